// Round 8
// baseline (45.507 us; speedup 1.0000x reference)
//
#include <hip/hip_runtime.h>
#include <math.h>

#define G 24
#define NPTS (G * G)      // 576
#define ROWS (NPTS + 1)   // 577
#define HD 64
#define BH (8 * 12)       // 96
#define EPSF 0.1f
#define COEFF 576.0f
#define BSHIFT 6.3543700408f  // log(575)
#define RPB 16                // rows per block
#define BPI ((ROWS + RPB - 1) / RPB)  // 37 blocks per image

typedef float f32x4 __attribute__((ext_vector_type(4)));

__global__ __launch_bounds__(256) void gaussian_augment_kernel(
    const float* __restrict__ q,
    const float* __restrict__ Wv,
    const float* __restrict__ bv,
    const float* __restrict__ Wa,
    const float* __restrict__ ba,
    float* __restrict__ out)
{
    const int bh  = blockIdx.x / BPI;
    const int blk = blockIdx.x - bh * BPI;
    const int r0  = blk * RPB;
    const int Ract = min(RPB, ROWS - r0);
    const int tid = threadIdx.x;

    __shared__ float s_part[RPB][16][3];           // dot-product partials
    __shared__ float s_par[RPB][4];                // inv0, inv1, alpha
    __shared__ __align__(16) float s_ex0[RPB][32]; // alpha*exp(-.5*(in-k)^2*inv0), k=0..23
    __shared__ __align__(16) float s_ex1[RPB][32]; // exp(-.5*(jn-k)^2*inv1),      k=0..23

    // ---- Phase 1: vectorized partial dot products (no shuffles) ----
    {
        const int r  = tid >> 4;   // 0..15
        const int kk = tid & 15;   // 4*kk..4*kk+3 of head_dim
        float p0 = 0.f, p1 = 0.f, p2 = 0.f;
        if (r < Ract) {
            const float* qp = q + ((size_t)bh * ROWS + r0 + r) * HD + 4 * kk;
            const f32x4 qv  = *(const f32x4*)qp;
            const f32x4 wv0 = *(const f32x4*)(Wv + 8 * kk);
            const f32x4 wv1 = *(const f32x4*)(Wv + 8 * kk + 4);
            const f32x4 wav = *(const f32x4*)(Wa + 4 * kk);
            p0 = qv[0]*wv0[0] + qv[1]*wv0[2] + qv[2]*wv1[0] + qv[3]*wv1[2];
            p1 = qv[0]*wv0[1] + qv[1]*wv0[3] + qv[2]*wv1[1] + qv[3]*wv1[3];
            p2 = qv[0]*wav[0] + qv[1]*wav[1] + qv[2]*wav[2] + qv[3]*wav[3];
        }
        s_part[r][kk][0] = p0;
        s_part[r][kk][1] = p1;
        s_part[r][kk][2] = p2;
    }
    __syncthreads();

    // ---- Phase 2: finish sums + transcendentals, one thread per (row,param) ----
    if (tid < 3 * RPB) {
        const int pr = tid / 3;
        const int pp = tid - 3 * pr;
        if (pr < Ract) {
            float x = 0.f;
            #pragma unroll
            for (int k = 0; k < 16; ++k) x += s_part[pr][k][pp];
            float o;
            if (pp == 2) {
                const float xa = x + ba[0];
                float al = fmaxf(xa, 0.f) + log1pf(expf(-fabsf(xa)));
                if (r0 + pr == 0) al = 0.f;   // prefix pad row -> zeros
                o = al;
            } else {
                const float xx = x + bv[pp] - BSHIFT;
                const float var = COEFF / (1.f + expf(-xx));
                o = 1.f / (var + EPSF);
            }
            s_par[pr][pp] = o;
        }
    }
    __syncthreads();

    // ---- Phase 3: absolute-indexed tables, 48 entries per row ----
    for (int e = tid; e < 48 * Ract; e += 256) {
        const int rr = (int)((unsigned)e / 48u);
        const int k  = e - 48 * rr;
        const int rg = r0 + rr;
        const int n  = (rg > 0) ? rg - 1 : 0;
        const int in_ = (int)((unsigned)n / 24u);
        const int jn_ = n - in_ * 24;
        if (k < 24) {
            const float t = (float)(in_ - k);
            s_ex0[rr][k] = s_par[rr][2] * expf(-0.5f * t * t * s_par[rr][0]);
        } else {
            const float t = (float)(jn_ - (k - 24));
            s_ex1[rr][k - 24] = expf(-0.5f * t * t * s_par[rr][1]);
        }
    }
    __syncthreads();

    // ---- Phase 4: pad column (c = 0) ----
    if (tid < Ract) {
        out[((size_t)bh * ROWS + r0 + tid) * ROWS] = 0.0f;
    }

    // ---- Phase 5: main stream — m-grid-aligned chunks, constant im per chunk ----
    // per iteration/thread: 1 ds_read_b32 + 1 ds_read_b128 + ~12 VALU + 1 dwordx4 store
    {
        const int r = tid >> 4;    // 0..15
        const int l = tid & 15;
        if (r < Ract) {
            float* rowp = out + ((size_t)bh * ROWS + r0 + r) * ROWS + 1;
            const float* e0p = s_ex0[r];
            const float* e1p = s_ex1[r];
            #pragma unroll
            for (int it = 0; it < 9; ++it) {
                const int k  = l + 16 * it;           // 0..143
                const int im = (int)((unsigned)k / 6u);
                const int u  = k - 6 * im;
                const float  e0 = e0p[im];
                const f32x4  e1 = *(const f32x4*)(e1p + 4 * u);
                f32x4 pk;
                pk[0] = e0 * e1[0];
                pk[1] = e0 * e1[1];
                pk[2] = e0 * e1[2];
                pk[3] = e0 * e1[3];
                __builtin_nontemporal_store(pk, (f32x4*)(rowp + 4 * k));
            }
        }
    }
}

extern "C" void kernel_launch(void* const* d_in, const int* in_sizes, int n_in,
                              void* d_out, int out_size, void* d_ws, size_t ws_size,
                              hipStream_t stream) {
    const float* q  = (const float*)d_in[0];
    const float* Wv = (const float*)d_in[1];
    const float* bv = (const float*)d_in[2];
    const float* Wa = (const float*)d_in[3];
    const float* ba = (const float*)d_in[4];
    float* out = (float*)d_out;

    const int grid = BH * BPI;  // 96 * 37 = 3552 blocks
    gaussian_augment_kernel<<<grid, 256, 0, stream>>>(q, Wv, bv, Wa, ba, out);
}

// Round 9
// 40.193 us; speedup vs baseline: 1.1322x; 1.1322x over previous
//
#include <hip/hip_runtime.h>
#include <math.h>

#define G 24
#define ROWS 577
#define HD 64
#define BH 96
#define EPSF 0.1f
#define COEFF 576.0f
#define BSHIFT 6.3543700408f   // log(575)
#define PAIRS 289              // row-pairs per image (last is single row)
#define NWAVES 6936            // 96*289/4
#define NBLOCKS 1734           // persistent: all resident, 4 waves each
#define PPW 4                  // pairs per wave: 6936*4 = 27744 = 96*289

typedef float f32x4 __attribute__((ext_vector_type(4)));

// LDS region per (wave,buf): 128 floats.
//  [0..25)  e0 (25 entries, [24] = safe dummy), alpha folded in
//  [32..60) e1dup (28 entries: e1[j mod 24])
//  [64..)   same for row B
__global__ __launch_bounds__(256) void gaussian_augment_kernel(
    const float* __restrict__ q,
    const float* __restrict__ Wv,
    const float* __restrict__ bv,
    const float* __restrict__ Wa,
    const float* __restrict__ ba,
    float* __restrict__ out)
{
    __shared__ float s_tab[4 * 2 * 128];

    const int tid  = threadIdx.x;
    const int lane = tid & 63;
    const int wv   = tid >> 6;
    float* const tbase = &s_tab[wv * 256];

    // ---- once-per-wave constants ----
    const int ll = lane & 15;              // dim-group 0..15
    const int rowB = (lane >> 4) & 1;      // groups 1,3 handle row B
    const f32x4 w0 = *(const f32x4*)(Wv + 8 * ll);
    const f32x4 w1 = *(const f32x4*)(Wv + 8 * ll + 4);
    const f32x4 wa = *(const f32x4*)(Wa + 4 * ll);
    const float bv0 = bv[0], bv1 = bv[1], ba0 = ba[0];

    const int gw = blockIdx.x * 4 + wv;    // 0..6935

    // ---------- helpers as macros (keep everything in registers) ----------
    // pair p -> bh, rA
#define PAIR_DECODE(p, bh_, rA_)                                            \
    const int bh_ = (int)((unsigned)(p) / (unsigned)PAIRS);                 \
    const int rA_ = 2 * ((p) - bh_ * PAIRS);

    // issue q loads for pair p (no wait)
#define QLOAD(p, qreg)                                                      \
    {                                                                       \
        PAIR_DECODE(p, bh_, rA_)                                            \
        const int rBofs = (rA_ + 1 < ROWS) ? HD : 0;                        \
        const float* qp = q + ((size_t)bh_ * ROWS + rA_) * HD               \
                            + rowB * rBofs + 4 * ll;                        \
        qreg = *(const f32x4*)qp;                                           \
    }

    // build tables for pair p from qreg into LDS at tb
#define BUILD(p, qreg, tb)                                                  \
    {                                                                       \
        PAIR_DECODE(p, bh_, rA_)                                            \
        float p0 = qreg[0]*w0[0] + qreg[1]*w0[2] + qreg[2]*w1[0] + qreg[3]*w1[2]; \
        float p1 = qreg[0]*w0[1] + qreg[1]*w0[3] + qreg[2]*w1[1] + qreg[3]*w1[3]; \
        float p2 = qreg[0]*wa[0] + qreg[1]*wa[1] + qreg[2]*wa[2] + qreg[3]*wa[3]; \
        p0 += __shfl_xor(p0, 1); p1 += __shfl_xor(p1, 1); p2 += __shfl_xor(p2, 1); \
        p0 += __shfl_xor(p0, 2); p1 += __shfl_xor(p1, 2); p2 += __shfl_xor(p2, 2); \
        p0 += __shfl_xor(p0, 4); p1 += __shfl_xor(p1, 4); p2 += __shfl_xor(p2, 4); \
        p0 += __shfl_xor(p0, 8); p1 += __shfl_xor(p1, 8); p2 += __shfl_xor(p2, 8); \
        const float a0 = __shfl(p0, 0),  a1 = __shfl(p1, 0),  a2 = __shfl(p2, 0);  \
        const float b0 = __shfl(p0, 16), b1 = __shfl(p1, 16), b2 = __shfl(p2, 16); \
        const float invA0 = 1.f / (COEFF / (1.f + expf(-(a0 + bv0 - BSHIFT))) + EPSF); \
        const float invA1 = 1.f / (COEFF / (1.f + expf(-(a1 + bv1 - BSHIFT))) + EPSF); \
        const float invB0 = 1.f / (COEFF / (1.f + expf(-(b0 + bv0 - BSHIFT))) + EPSF); \
        const float invB1 = 1.f / (COEFF / (1.f + expf(-(b1 + bv1 - BSHIFT))) + EPSF); \
        const float xaA = a2 + ba0;                                         \
        float alphaA = fmaxf(xaA, 0.f) + log1pf(expf(-fabsf(xaA)));         \
        if (rA_ == 0) alphaA = 0.f;                                         \
        const float xaB = b2 + ba0;                                         \
        const float alphaB = fmaxf(xaB, 0.f) + log1pf(expf(-fabsf(xaB)));   \
        const int nA = (rA_ > 0) ? rA_ - 1 : 0;                             \
        const int iA = (int)((unsigned)nA / 24u); const int jA = nA - 24 * iA; \
        const int nB = rA_;                                                 \
        const int iB = (int)((unsigned)nB / 24u); const int jB = nB - 24 * iB; \
        if (lane < 53) {                                                    \
            const bool isE0 = lane < 25;                                    \
            const int  j    = lane - 25;                                    \
            const int  jm   = (j >= 24) ? j - 24 : j;                       \
            const int  o    = isE0 ? lane : 32 + j;                         \
            const float tA = isE0 ? (float)(iA - lane) : (float)(jA - jm);  \
            const float sA = isE0 ? invA0 : invA1;                          \
            const float mA = isE0 ? alphaA : 1.f;                           \
            (tb)[o] = mA * expf(-0.5f * tA * tA * sA);                      \
            const float tB = isE0 ? (float)(iB - lane) : (float)(jB - jm);  \
            const float sB = isE0 ? invB0 : invB1;                          \
            const float mB = isE0 ? alphaB : 1.f;                           \
            (tb)[64 + o] = mB * expf(-0.5f * tB * tB * sB);                 \
        }                                                                   \
    }

    // stream pair p using tables at tb
#define STREAM(p, tb)                                                       \
    {                                                                       \
        PAIR_DECODE(p, bh_, rA_)                                            \
        const int span = (rA_ + 1 < ROWS) ? 2 * ROWS : ROWS;                \
        const size_t base = ((size_t)bh_ * ROWS + rA_) * ROWS;              \
        const size_t S0 = base & ~(size_t)3;                                \
        const int off = (int)(base - S0);                                   \
        const int nch = (span + off + 3) >> 2;                              \
        for (int it = 0; it < 5; ++it) {                                    \
            const int idx = lane + 64 * it;                                 \
            if (idx < nch) {                                                \
                const int e0i = 4 * idx - off;                              \
                const int rr  = (e0i >= ROWS) ? 1 : 0;                      \
                const int c0  = e0i - (rr ? ROWS : 0);                      \
                const float* tbl = (tb) + (rr ? 64 : 0);                    \
                const size_t g0 = S0 + (size_t)4 * idx;                     \
                if (e0i >= 0 && e0i + 4 <= span && c0 >= 1 && c0 <= 573) {  \
                    const int m0  = c0 - 1;                                 \
                    const int im0 = (int)((unsigned)m0 / 24u);              \
                    const int jm0 = m0 - 24 * im0;                          \
                    const float x0 = tbl[im0], x1 = tbl[im0 + 1];           \
                    const float e1a = tbl[32 + jm0];                        \
                    const float e1b = tbl[32 + jm0 + 1];                    \
                    const float e1c = tbl[32 + jm0 + 2];                    \
                    const float e1d = tbl[32 + jm0 + 3];                    \
                    f32x4 pk;                                               \
                    pk[0] = x0 * e1a;                                       \
                    pk[1] = (jm0 >= 23 ? x1 : x0) * e1b;                    \
                    pk[2] = (jm0 >= 22 ? x1 : x0) * e1c;                    \
                    pk[3] = (jm0 >= 21 ? x1 : x0) * e1d;                    \
                    __builtin_nontemporal_store(pk, (f32x4*)(out + g0));    \
                } else {                                                    \
                    _Pragma("unroll")                                       \
                    for (int t = 0; t < 4; ++t) {                           \
                        const int e = e0i + t;                              \
                        if (e >= 0 && e < span) {                           \
                            const int rr2 = (e >= ROWS) ? 1 : 0;            \
                            const int c   = e - (rr2 ? ROWS : 0);           \
                            float val = 0.f;                                \
                            if (c > 0) {                                    \
                                const unsigned m = (unsigned)(c - 1);       \
                                const int im = (int)(m / 24u);              \
                                const int jm = (int)m - 24 * im;            \
                                const float* t2 = (tb) + rr2 * 64;          \
                                val = t2[im] * t2[32 + jm];                 \
                            }                                               \
                            out[g0 + t] = val;                              \
                        }                                                   \
                    }                                                       \
                }                                                           \
            }                                                               \
        }                                                                   \
    }

    // ---------- pipelined main: zero barriers ----------
    f32x4 qr;
    QLOAD(gw, qr);
    BUILD(gw, qr, tbase);               // buf 0

    {
        f32x4 qn;
        // k = 0
        QLOAD(gw + 1 * NWAVES, qn);
        STREAM(gw, tbase);
        BUILD(gw + 1 * NWAVES, qn, tbase + 128);
        // k = 1
        QLOAD(gw + 2 * NWAVES, qn);
        STREAM(gw + 1 * NWAVES, tbase + 128);
        BUILD(gw + 2 * NWAVES, qn, tbase);
        // k = 2
        QLOAD(gw + 3 * NWAVES, qn);
        STREAM(gw + 2 * NWAVES, tbase);
        BUILD(gw + 3 * NWAVES, qn, tbase + 128);
        // k = 3
        STREAM(gw + 3 * NWAVES, tbase + 128);
    }
}

extern "C" void kernel_launch(void* const* d_in, const int* in_sizes, int n_in,
                              void* d_out, int out_size, void* d_ws, size_t ws_size,
                              hipStream_t stream) {
    const float* q  = (const float*)d_in[0];
    const float* Wv = (const float*)d_in[1];
    const float* bv = (const float*)d_in[2];
    const float* Wa = (const float*)d_in[3];
    const float* ba = (const float*)d_in[4];
    float* out = (float*)d_out;

    gaussian_augment_kernel<<<NBLOCKS, 256, 0, stream>>>(q, Wv, bv, Wa, ba, out);
}